// Round 1
// baseline (319.642 us; speedup 1.0000x reference)
//
#include <hip/hip_runtime.h>
#include <math.h>

#define BSZ 4096
#define DIM 128
#define K_TOP 200

// ---- monotone float<->uint mapping (order-preserving) ----
__device__ inline unsigned fmap(float s) {
    unsigned b = __float_as_uint(s);
    return (b & 0x80000000u) ? ~b : (b | 0x80000000u);
}
__device__ inline float finv(unsigned u) {
    unsigned b = (u & 0x80000000u) ? (u & 0x7fffffffu) : ~u;
    return __uint_as_float(b);
}

__device__ inline float blockReduceSumF(float v, float* red) {
    #pragma unroll
    for (int o = 32; o > 0; o >>= 1) v += __shfl_down(v, o);
    const int tid = threadIdx.x;
    if ((tid & 63) == 0) red[tid >> 6] = v;
    __syncthreads();
    if (tid == 0) red[0] = red[0] + red[1] + red[2] + red[3];
    __syncthreads();
    float r = red[0];
    __syncthreads();
    return r;
}

// ---------------- Kernel 1: S = A * A^T  (A: 4096x128 fp32) ----------------
__global__ __launch_bounds__(256) void gemm_aat(const float* __restrict__ A,
                                                float* __restrict__ S) {
    __shared__ float As[64][65];
    __shared__ float Bs[64][65];
    const int bx = blockIdx.x, by = blockIdx.y;
    const int tid = threadIdx.x;
    const int tx = tid & 15, ty = tid >> 4;
    const int row0a = by * 64, row0b = bx * 64;
    float acc[4][4] = {};

    for (int k0 = 0; k0 < DIM; k0 += 64) {
        __syncthreads();
        // stage 64x64 chunks of both tiles
        for (int q = tid; q < 1024; q += 256) {
            int r  = q >> 4;   // 16 float4 per row of 64 floats
            int c4 = q & 15;
            float4 va = *(const float4*)(A + (size_t)(row0a + r) * DIM + k0 + c4 * 4);
            float4 vb = *(const float4*)(A + (size_t)(row0b + r) * DIM + k0 + c4 * 4);
            As[r][c4 * 4 + 0] = va.x; As[r][c4 * 4 + 1] = va.y;
            As[r][c4 * 4 + 2] = va.z; As[r][c4 * 4 + 3] = va.w;
            Bs[r][c4 * 4 + 0] = vb.x; Bs[r][c4 * 4 + 1] = vb.y;
            Bs[r][c4 * 4 + 2] = vb.z; Bs[r][c4 * 4 + 3] = vb.w;
        }
        __syncthreads();
        #pragma unroll 8
        for (int k = 0; k < 64; ++k) {
            float a0 = As[ty * 4 + 0][k], a1 = As[ty * 4 + 1][k];
            float a2 = As[ty * 4 + 2][k], a3 = As[ty * 4 + 3][k];
            float b0 = Bs[tx * 4 + 0][k], b1 = Bs[tx * 4 + 1][k];
            float b2 = Bs[tx * 4 + 2][k], b3 = Bs[tx * 4 + 3][k];
            acc[0][0] += a0 * b0; acc[0][1] += a0 * b1; acc[0][2] += a0 * b2; acc[0][3] += a0 * b3;
            acc[1][0] += a1 * b0; acc[1][1] += a1 * b1; acc[1][2] += a1 * b2; acc[1][3] += a1 * b3;
            acc[2][0] += a2 * b0; acc[2][1] += a2 * b1; acc[2][2] += a2 * b2; acc[2][3] += a2 * b3;
            acc[3][0] += a3 * b0; acc[3][1] += a3 * b1; acc[3][2] += a3 * b2; acc[3][3] += a3 * b3;
        }
    }
    #pragma unroll
    for (int ii = 0; ii < 4; ++ii) {
        float4 v = make_float4(acc[ii][0], acc[ii][1], acc[ii][2], acc[ii][3]);
        *(float4*)(S + (size_t)(row0a + ty * 4 + ii) * BSZ + row0b + tx * 4) = v;
    }
}

// ---------------- radix select helper ----------------
// hist[nbins] populated; finds bin b s.t. count(bins > b) < Kwant <= count(bins >= b).
// Returns sel[0]=b, sel[1]=count strictly above b. All 256 threads participate.
__device__ void radix_select(int* hist, int* coarse, int* sel, int nbins, int Kwant) {
    const int tid = threadIdx.x;
    const int cs = nbins >> 8;  // 16 (4096 bins) or 1 (256 bins)
    int cnt = 0;
    for (int t = 0; t < cs; ++t) cnt += hist[tid * cs + t];
    coarse[tid] = cnt;
    __syncthreads();
    // Hillis-Steele inclusive suffix scan over 256 entries
    for (int off = 1; off < 256; off <<= 1) {
        int add = (tid + off < 256) ? coarse[tid + off] : 0;
        __syncthreads();
        coarse[tid] += add;
        __syncthreads();
    }
    int above = coarse[tid] - cnt;
    if (above < Kwant && above + cnt >= Kwant) { sel[0] = tid; sel[1] = above; }
    __syncthreads();
    if (tid == 0) {
        int chunk = sel[0], acc = sel[1], b = chunk * cs;
        for (int fb = chunk * cs + cs - 1; fb >= chunk * cs; --fb) {
            int h = hist[fb];
            if (acc + h >= Kwant) { b = fb; break; }
            acc += h;
        }
        sel[0] = b; sel[1] = acc;
    }
    __syncthreads();
}

// ---------------- Kernel 2: per-row stats + exact top-k + loss ----------------
__global__ __launch_bounds__(256) void row_stats_kernel(const float* __restrict__ S,
                                                        const float* __restrict__ F,
                                                        const int* __restrict__ labels,
                                                        float* __restrict__ accum,
                                                        int fused) {
    __shared__ float s_row[BSZ];
    __shared__ int   lab_sh[BSZ];
    __shared__ int   hist[4096];
    __shared__ int   coarse[256];
    __shared__ int   sel[2];
    __shared__ float redf[4];
    __shared__ float fi_sh[DIM];

    const int i = blockIdx.x;
    const int tid = threadIdx.x;

    for (int q = tid; q < 4096; q += 256) hist[q] = 0;
    for (int q = tid; q < BSZ / 4; q += 256)
        ((int4*)lab_sh)[q] = ((const int4*)labels)[q];

    float mx = -2.0f;
    if (!fused) {
        const float* row = S + (size_t)i * BSZ;
        for (int q = tid; q < BSZ / 4; q += 256) {
            float4 v = ((const float4*)row)[q];
            ((float4*)s_row)[q] = v;
            mx = fmaxf(mx, fmaxf(fmaxf(v.x, v.y), fmaxf(v.z, v.w)));
        }
    } else {
        if (tid < DIM / 4) ((float4*)fi_sh)[tid] = ((const float4*)(F + (size_t)i * DIM))[tid];
        __syncthreads();
        for (int j = tid; j < BSZ; j += 256) {
            const float4* fj = (const float4*)(F + (size_t)j * DIM);
            float acc = 0.f;
            #pragma unroll 8
            for (int c = 0; c < DIM / 4; ++c) {
                float4 a = ((const float4*)fi_sh)[c];
                float4 b = fj[c];
                acc += a.x * b.x + a.y * b.y + a.z * b.z + a.w * b.w;
            }
            s_row[j] = acc;
            mx = fmaxf(mx, acc);
        }
    }
    __syncthreads();

    // block max
    #pragma unroll
    for (int o = 32; o > 0; o >>= 1) mx = fmaxf(mx, __shfl_down(mx, o));
    if ((tid & 63) == 0) redf[tid >> 6] = mx;
    __syncthreads();
    if (tid == 0) redf[0] = fmaxf(fmaxf(redf[0], redf[1]), fmaxf(redf[2], redf[3]));
    __syncthreads();
    const float M = redf[0];
    const int lab_i = lab_sh[i];
    __syncthreads();

    // positives pass + pass-1 histogram (bits 31..20 of mapped negatives)
    float psum = 0.f, pexp = 0.f;
    int pcnt = 0;
    for (int q = tid; q < BSZ; q += 256) {
        if (q == i) continue;
        float s = s_row[q];
        if (lab_sh[q] == lab_i) {
            pcnt++; psum += s; pexp += expf((s - M) * 10.f);
        } else {
            unsigned u = fmap(s);
            atomicAdd(&hist[u >> 20], 1);
        }
    }
    __syncthreads();

    psum = blockReduceSumF(psum, redf);
    pexp = blockReduceSumF(pexp, redf);
    float pcntf = blockReduceSumF((float)pcnt, redf);

    radix_select(hist, coarse, sel, 4096, K_TOP);
    const int b1 = sel[0], c1 = sel[1];
    __syncthreads();
    for (int q = tid; q < 4096; q += 256) hist[q] = 0;
    __syncthreads();

    const int K2 = K_TOP - c1;
    for (int q = tid; q < BSZ; q += 256) {
        if (q == i || lab_sh[q] == lab_i) continue;
        unsigned u = fmap(s_row[q]);
        if ((int)(u >> 20) == b1) atomicAdd(&hist[(u >> 8) & 0xFFF], 1);
    }
    __syncthreads();
    radix_select(hist, coarse, sel, 4096, K2);
    const int b2 = sel[0], c2 = sel[1];
    __syncthreads();
    hist[tid] = 0;  // only 256 bins needed for pass 3
    __syncthreads();

    const int K3 = K2 - c2;
    const unsigned pref = ((unsigned)b1 << 12) | (unsigned)b2;
    for (int q = tid; q < BSZ; q += 256) {
        if (q == i || lab_sh[q] == lab_i) continue;
        unsigned u = fmap(s_row[q]);
        if ((u >> 8) == pref) atomicAdd(&hist[u & 0xFF], 1);
    }
    __syncthreads();
    radix_select(hist, coarse, sel, 256, K3);
    const int b3 = sel[0], c3 = sel[1];
    __syncthreads();

    const unsigned tbits = ((unsigned)b1 << 20) | ((unsigned)b2 << 8) | (unsigned)b3;
    const int nAt = K3 - c3;  // ties included at threshold value

    float te = 0.f;
    for (int q = tid; q < BSZ; q += 256) {
        if (q == i || lab_sh[q] == lab_i) continue;
        float s = s_row[q];
        if (fmap(s) > tbits) te += expf((s - M) * 10.f);
    }
    te = blockReduceSumF(te, redf);

    if (tid == 0) {
        float tval  = finv(tbits);
        float topk  = te + (float)nAt * expf((tval - M) * 10.f);
        float denom = pexp + topk;
        bool valid = (lab_i > 0) && (pcntf > 0.f);
        if (valid) {
            float sum_logprob = 10.f * (psum - pcntf * M) - pcntf * logf(denom);
            float per_row = -2.f * (sum_logprob / pcntf);
            atomicAdd(&accum[0], per_row);
            atomicAdd(&accum[1], 1.f);
        }
    }
}

__global__ void init_kernel(float* accum) {
    accum[0] = 0.f;
    accum[1] = 0.f;
}

__global__ void finalize_kernel(const float* __restrict__ accum, float* __restrict__ out) {
    out[0] = accum[0] / accum[1];
}

extern "C" void kernel_launch(void* const* d_in, const int* in_sizes, int n_in,
                              void* d_out, int out_size, void* d_ws, size_t ws_size,
                              hipStream_t stream) {
    const float* F      = (const float*)d_in[0];
    const int*   labels = (const int*)d_in[1];
    float*       out    = (float*)d_out;

    const size_t sbytes = (size_t)BSZ * BSZ * sizeof(float);
    const bool useS = ws_size >= sbytes + 64;

    float* S     = (float*)d_ws;
    float* accum = useS ? (float*)((char*)d_ws + sbytes) : (float*)d_ws;

    init_kernel<<<1, 1, 0, stream>>>(accum);
    if (useS) {
        gemm_aat<<<dim3(64, 64), 256, 0, stream>>>(F, S);
    }
    row_stats_kernel<<<BSZ, 256, 0, stream>>>(useS ? S : nullptr, F, labels, accum,
                                              useS ? 0 : 1);
    finalize_kernel<<<1, 1, 0, stream>>>(accum, out);
}

// Round 2
// 228.350 us; speedup vs baseline: 1.3998x; 1.3998x over previous
//
#include <hip/hip_runtime.h>
#include <math.h>

#define BSZ 4096
#define DIM 128
#define K_TOP 200
#define CAND_MAX 2048

// ---- monotone float<->uint mapping (order-preserving) ----
__device__ inline unsigned fmap(float s) {
    unsigned b = __float_as_uint(s);
    return (b & 0x80000000u) ? ~b : (b | 0x80000000u);
}
__device__ inline float finv(unsigned u) {
    unsigned b = (u & 0x80000000u) ? (u & 0x7fffffffu) : ~u;
    return __uint_as_float(b);
}
__device__ inline short f2bf(float x) {  // fp32 -> bf16 RNE
    unsigned u = __float_as_uint(x);
    unsigned r = (u + 0x7fffu + ((u >> 16) & 1u)) >> 16;
    return (short)(unsigned short)r;
}

typedef __attribute__((ext_vector_type(8))) short bf16x8;
typedef __attribute__((ext_vector_type(4))) float floatx4;

__device__ inline bf16x8 pack8(const float* __restrict__ p) {
    float4 x = *(const float4*)p;
    float4 y = *(const float4*)(p + 4);
    bf16x8 r;
    r[0] = f2bf(x.x); r[1] = f2bf(x.y); r[2] = f2bf(x.z); r[3] = f2bf(x.w);
    r[4] = f2bf(y.x); r[5] = f2bf(y.y); r[6] = f2bf(y.z); r[7] = f2bf(y.w);
    return r;
}

// ---------------- Kernel 1: S = F * F^T via bf16 MFMA ----------------
// Each wave computes a 64x64 tile (4x4 of 16x16x32 MFMA). Block = 4 waves
// covering 128x128. Fragments load directly from global (F is 2 MB, hot in
// L1/L2); inline fp32->bf16 conversion avoids any workspace staging.
// A-frag: A[m=lane&15][k=quad*8+j]; B=F^T so B-frag loads F rows too.
// C/D: col=lane&15, row=quad*4+reg (m89/m120-verified). S symmetric -> any
// residual transpose ambiguity is harmless.
__global__ __launch_bounds__(256) void gemm_mfma(const float* __restrict__ F,
                                                 float* __restrict__ S) {
    const int tid = threadIdx.x;
    const int wave = tid >> 6, lane = tid & 63;
    const int l16 = lane & 15, quad = lane >> 4;
    const int row0 = blockIdx.y * 128 + (wave >> 1) * 64;
    const int col0 = blockIdx.x * 128 + (wave & 1) * 64;

    floatx4 acc[4][4];
    #pragma unroll
    for (int mt = 0; mt < 4; ++mt)
        #pragma unroll
        for (int nt = 0; nt < 4; ++nt)
            acc[mt][nt] = (floatx4){0.f, 0.f, 0.f, 0.f};

    for (int ks = 0; ks < DIM; ks += 32) {
        bf16x8 a[4], b[4];
        #pragma unroll
        for (int t = 0; t < 4; ++t) {
            a[t] = pack8(F + (size_t)(row0 + t * 16 + l16) * DIM + ks + quad * 8);
            b[t] = pack8(F + (size_t)(col0 + t * 16 + l16) * DIM + ks + quad * 8);
        }
        #pragma unroll
        for (int mt = 0; mt < 4; ++mt)
            #pragma unroll
            for (int nt = 0; nt < 4; ++nt)
                acc[mt][nt] = __builtin_amdgcn_mfma_f32_16x16x32_bf16(
                    a[mt], b[nt], acc[mt][nt], 0, 0, 0);
    }
    #pragma unroll
    for (int mt = 0; mt < 4; ++mt) {
        const int r0 = row0 + mt * 16 + quad * 4;
        #pragma unroll
        for (int nt = 0; nt < 4; ++nt) {
            const int c = col0 + nt * 16 + l16;
            #pragma unroll
            for (int e = 0; e < 4; ++e)
                S[(size_t)(r0 + e) * BSZ + c] = acc[mt][nt][e];
        }
    }
}

// ---------------- radix select (low-barrier version) ----------------
// hist[nbins] -> bin b with count(>b) < Kwant <= count(>=b).
// sel[0]=b, sel[1]=count strictly above b. 3 barriers total.
__device__ void radix_select(const int* hist, volatile int* wtot, volatile int* sel,
                             int nbins, int Kwant) {
    const int tid = threadIdx.x, lane = tid & 63, w = tid >> 6;
    const int cs = nbins >> 8;
    const int base = tid * cs;
    int cnt = 0;
    for (int t = 0; t < cs; ++t) cnt += hist[base + t];
    int v = cnt;
    #pragma unroll
    for (int off = 1; off < 64; off <<= 1) {   // wave-internal suffix sum
        int t = __shfl_down(v, off);
        if (lane + off < 64) v += t;
    }
    if (lane == 0) wtot[w] = v;                // wave total
    __syncthreads();
    int later = 0;
    for (int ww = w + 1; ww < 4; ++ww) later += wtot[ww];
    const int incl = v + later;                // sum of chunks tid..255
    const int above = incl - cnt;
    if (above < Kwant && incl >= Kwant) {      // exactly one thread matches
        int acc = above, b = base;
        for (int fb = base + cs - 1; fb >= base; --fb) {
            int h = hist[fb];
            if (acc + h >= Kwant) { b = fb; break; }
            acc += h;
        }
        sel[0] = b; sel[1] = acc;
    }
    __syncthreads();
}

__device__ inline void blockReduce3(float& a, float& b, float& c, volatile float* red) {
    const int lane = threadIdx.x & 63, w = threadIdx.x >> 6;
    #pragma unroll
    for (int off = 32; off > 0; off >>= 1) {
        a += __shfl_down(a, off);
        b += __shfl_down(b, off);
        c += __shfl_down(c, off);
    }
    if (lane == 0) { red[w * 3 + 0] = a; red[w * 3 + 1] = b; red[w * 3 + 2] = c; }
    __syncthreads();
    a = red[0] + red[3] + red[6] + red[9];
    b = red[1] + red[4] + red[7] + red[10];
    c = red[2] + red[5] + red[8] + red[11];
    __syncthreads();
}

__device__ inline float blockReduce1(float a, volatile float* red) {
    const int lane = threadIdx.x & 63, w = threadIdx.x >> 6;
    #pragma unroll
    for (int off = 32; off > 0; off >>= 1) a += __shfl_down(a, off);
    if (lane == 0) red[w] = a;
    __syncthreads();
    float r = red[0] + red[1] + red[2] + red[3];
    __syncthreads();
    return r;
}

// ---------------- Kernel 2: per-row stats + exact top-k + loss ----------------
// Loss is shift-invariant in the row max, so use fixed M=1.0 (s<=1).
// Scan A: load row, positive stats, 11-bit histogram of negatives.
// Scan B: exp-sum elements strictly above threshold bin; collect threshold-bin
// candidates into an LDS list (expected ~150). Refine top-k threshold over the
// candidate list only (two more radix passes). Ties handled exactly by value.
__global__ __launch_bounds__(256) void row_stats2(const float* __restrict__ S,
                                                  const int* __restrict__ labels,
                                                  float* __restrict__ accum) {
    __shared__ float s_row[BSZ];            // 16 KB
    __shared__ unsigned labw[BSZ / 4];      // 4 KB (labels as u8)
    __shared__ int hist[2048];              // 8 KB
    __shared__ unsigned cand[CAND_MAX];     // 8 KB
    __shared__ int wtot[4];
    __shared__ int sel[2];
    __shared__ float redf[12];
    __shared__ int ncand_sh;

    const int i = blockIdx.x;
    const int tid = threadIdx.x;
    const int labi = labels[i];

    for (int q = tid; q < 2048; q += 256) hist[q] = 0;
    for (int q = tid; q < BSZ / 4; q += 256) {
        int4 v = ((const int4*)labels)[q];
        labw[q] = (unsigned)(v.x & 0xFF) | ((unsigned)(v.y & 0xFF) << 8) |
                  ((unsigned)(v.z & 0xFF) << 16) | ((unsigned)(v.w & 0xFF) << 24);
    }
    if (tid == 0) ncand_sh = 0;
    __syncthreads();

    // ---- scan A: load + positives + pass-1 histogram ----
    const float4* row4 = (const float4*)(S + (size_t)i * BSZ);
    float psum = 0.f, pexp = 0.f, pcntf = 0.f;
    for (int q = tid; q < BSZ / 4; q += 256) {
        float4 v = row4[q];
        ((float4*)s_row)[q] = v;
        unsigned lw = labw[q];
        int j0 = q * 4;
        #pragma unroll
        for (int c = 0; c < 4; ++c) {
            float s = (c == 0) ? v.x : (c == 1) ? v.y : (c == 2) ? v.z : v.w;
            int j = j0 + c;
            if (j == i) continue;
            if ((int)((lw >> (8 * c)) & 0xFF) == labi) {
                pcntf += 1.f; psum += s; pexp += __expf((s - 1.f) * 10.f);
            } else {
                atomicAdd(&hist[fmap(s) >> 21], 1);
            }
        }
    }
    __syncthreads();
    blockReduce3(psum, pexp, pcntf, redf);
    radix_select(hist, wtot, sel, 2048, K_TOP);
    const int b1 = sel[0], c1 = sel[1];
    const int K2 = K_TOP - c1;   // >= 1

    // ---- scan B: exp-sum above bin b1, collect bin-b1 candidates ----
    float te = 0.f;
    for (int q = tid; q < BSZ / 4; q += 256) {
        float4 v = ((const float4*)s_row)[q];
        unsigned lw = labw[q];
        int j0 = q * 4;
        #pragma unroll
        for (int c = 0; c < 4; ++c) {
            int j = j0 + c;
            if (j == i) continue;
            if ((int)((lw >> (8 * c)) & 0xFF) == labi) continue;
            float s = (c == 0) ? v.x : (c == 1) ? v.y : (c == 2) ? v.z : v.w;
            unsigned u = fmap(s);
            int bin = u >> 21;
            if (bin > b1) {
                te += __expf((s - 1.f) * 10.f);
            } else if (bin == b1) {
                int pos = atomicAdd(&ncand_sh, 1);
                if (pos < CAND_MAX) cand[pos] = u;
            }
        }
    }
    __syncthreads();
    const int nc = ncand_sh;
    int b2, c2, K3, b3, c3;
    unsigned tbits;

    if (nc <= CAND_MAX) {
        // ---- refine threshold over candidate list only ----
        for (int q = tid; q < 2048; q += 256) hist[q] = 0;
        __syncthreads();
        for (int q = tid; q < nc; q += 256) atomicAdd(&hist[(cand[q] >> 10) & 0x7FF], 1);
        __syncthreads();
        radix_select(hist, wtot, sel, 2048, K2);
        b2 = sel[0]; c2 = sel[1]; K3 = K2 - c2;
        for (int q = tid; q < 1024; q += 256) hist[q] = 0;
        __syncthreads();
        for (int q = tid; q < nc; q += 256) {
            unsigned u = cand[q];
            if (((u >> 10) & 0x7FF) == (unsigned)b2) atomicAdd(&hist[u & 0x3FF], 1);
        }
        __syncthreads();
        radix_select(hist, wtot, sel, 1024, K3);
        b3 = sel[0]; c3 = sel[1];
        tbits = ((unsigned)b1 << 21) | ((unsigned)b2 << 10) | (unsigned)b3;
        for (int q = tid; q < nc; q += 256) {
            unsigned u = cand[q];
            if (u > tbits) te += __expf((finv(u) - 1.f) * 10.f);
        }
    } else {
        // ---- fallback: full-scan refinement (candidate buffer overflow) ----
        for (int q = tid; q < 2048; q += 256) hist[q] = 0;
        __syncthreads();
        for (int q = tid; q < BSZ; q += 256) {
            if (q == i || (int)((labw[q >> 2] >> ((q & 3) * 8)) & 0xFF) == labi) continue;
            unsigned u = fmap(s_row[q]);
            if ((u >> 21) == (unsigned)b1) atomicAdd(&hist[(u >> 10) & 0x7FF], 1);
        }
        __syncthreads();
        radix_select(hist, wtot, sel, 2048, K2);
        b2 = sel[0]; c2 = sel[1]; K3 = K2 - c2;
        for (int q = tid; q < 1024; q += 256) hist[q] = 0;
        __syncthreads();
        for (int q = tid; q < BSZ; q += 256) {
            if (q == i || (int)((labw[q >> 2] >> ((q & 3) * 8)) & 0xFF) == labi) continue;
            unsigned u = fmap(s_row[q]);
            if ((u >> 10) == (((unsigned)b1 << 11) | (unsigned)b2)) atomicAdd(&hist[u & 0x3FF], 1);
        }
        __syncthreads();
        radix_select(hist, wtot, sel, 1024, K3);
        b3 = sel[0]; c3 = sel[1];
        tbits = ((unsigned)b1 << 21) | ((unsigned)b2 << 10) | (unsigned)b3;
        for (int q = tid; q < BSZ; q += 256) {
            if (q == i || (int)((labw[q >> 2] >> ((q & 3) * 8)) & 0xFF) == labi) continue;
            unsigned u = fmap(s_row[q]);
            if ((u >> 21) == (unsigned)b1 && u > tbits)
                te += __expf((s_row[q] - 1.f) * 10.f);
        }
    }

    float tesum = blockReduce1(te, redf);

    if (tid == 0) {
        const int nAt = K3 - c3;                 // ties included at threshold value
        float tval = finv(tbits);
        float topk = tesum + (float)nAt * __expf((tval - 1.f) * 10.f);
        float denom = pexp + topk;
        if (labi > 0 && pcntf > 0.f) {
            float sum_logprob = 10.f * (psum - pcntf) - pcntf * logf(denom);
            atomicAdd(&accum[0], -2.f * sum_logprob / pcntf);
            atomicAdd(&accum[1], 1.f);
        }
    }
}

__global__ void init_kernel(float* accum) {
    accum[0] = 0.f;
    accum[1] = 0.f;
}

__global__ void finalize_kernel(const float* __restrict__ accum, float* __restrict__ out) {
    out[0] = accum[0] / accum[1];
}

extern "C" void kernel_launch(void* const* d_in, const int* in_sizes, int n_in,
                              void* d_out, int out_size, void* d_ws, size_t ws_size,
                              hipStream_t stream) {
    const float* F      = (const float*)d_in[0];
    const int*   labels = (const int*)d_in[1];
    float*       out    = (float*)d_out;

    const size_t sbytes = (size_t)BSZ * BSZ * sizeof(float);
    float* S     = (float*)d_ws;
    float* accum = (float*)((char*)d_ws + sbytes);

    init_kernel<<<1, 1, 0, stream>>>(accum);
    gemm_mfma<<<dim3(32, 32), 256, 0, stream>>>(F, S);
    row_stats2<<<BSZ, 256, 0, stream>>>(S, labels, accum);
    finalize_kernel<<<1, 1, 0, stream>>>(accum, out);
}

// Round 3
// 194.412 us; speedup vs baseline: 1.6441x; 1.1746x over previous
//
#include <hip/hip_runtime.h>
#include <math.h>

#define BSZ 4096
#define DIM 128
#define K_TOP 200
#define NBINS 1024
#define CAND_CAP 256

typedef unsigned short u16;
typedef unsigned int u32;
typedef __attribute__((ext_vector_type(8))) short bf16x8;
typedef __attribute__((ext_vector_type(4))) float floatx4;

__device__ inline u16 f2bf(float x) {  // fp32 -> bf16 RNE
    u32 u = __float_as_uint(x);
    return (u16)((u + 0x7fffu + ((u >> 16) & 1u)) >> 16);
}
__device__ inline float bf2f(u16 b) { return __uint_as_float(((u32)b) << 16); }

// ---------------- pre: F -> bf16, labels -> u8, accum init ----------------
__global__ __launch_bounds__(256) void pre_kernel(const float* __restrict__ F,
                                                  const int* __restrict__ labels,
                                                  u16* __restrict__ Fb,
                                                  unsigned char* __restrict__ lab8,
                                                  float* __restrict__ accum) {
    int idx = blockIdx.x * 256 + threadIdx.x;
    if (idx < BSZ * DIM / 4) {
        float4 v = ((const float4*)F)[idx];
        ushort4 r;
        r.x = f2bf(v.x); r.y = f2bf(v.y); r.z = f2bf(v.z); r.w = f2bf(v.w);
        ((ushort4*)Fb)[idx] = r;
    }
    if (idx < BSZ / 4) {
        int4 lv = ((const int4*)labels)[idx];
        uchar4 r;
        r.x = (unsigned char)lv.x; r.y = (unsigned char)lv.y;
        r.z = (unsigned char)lv.z; r.w = (unsigned char)lv.w;
        ((uchar4*)lab8)[idx] = r;
    }
    if (idx == 0) { accum[0] = 0.f; accum[1] = 0.f; }
}

// ---------------- Kernel 1: S = Fb * Fb^T (bf16 MFMA, bf16 output) ----------------
// m97-style: global_load_lds width-16 staging of 128x32 tiles, ds_read_b128
// fragments, LDS-staged coalesced bf16 writeback. Block 256 = 4 waves (2x2
// quadrants of 64x64). Fragment k-map: A[m=lane&15][k=quad*8+j] (verified,
// same indices as the R2 kernel that passed with absmax 0).
__global__ __launch_bounds__(256) void gemm_bf16(const u16* __restrict__ Fb,
                                                 u16* __restrict__ S) {
    __shared__ u16 smem[128 * 132];          // 33792 B; As/Bs then reused as Cs
    u16* As = smem;                           // 128 rows x 32 cols
    u16* Bs = smem + 128 * 32;
    u16* Cs = smem;                           // 128 x 132 (pad -> conflict-free)

    const int tid  = threadIdx.x;
    const int wave = tid >> 6, lane = tid & 63;
    const int l16  = lane & 15, quad = lane >> 4;
    const int brow = blockIdx.y * 128, bcol = blockIdx.x * 128;
    const int wr = (wave >> 1) * 64, wc = (wave & 1) * 64;

    floatx4 acc[4][4];
    #pragma unroll
    for (int mt = 0; mt < 4; ++mt)
        #pragma unroll
        for (int nt = 0; nt < 4; ++nt)
            acc[mt][nt] = (floatx4){0.f, 0.f, 0.f, 0.f};

    for (int ks = 0; ks < DIM; ks += 32) {
        if (ks) __syncthreads();
        #pragma unroll
        for (int p = 0; p < 2; ++p) {
            int idx = p * 256 + tid;
            int row = idx >> 2, ch = idx & 3;     // 4 x 16B chunks per 32-col row
            const u16* ga = Fb + (size_t)(brow + row) * DIM + ks + ch * 8;
            const u16* gb = Fb + (size_t)(bcol + row) * DIM + ks + ch * 8;
            __builtin_amdgcn_global_load_lds(
                (const __attribute__((address_space(1))) void*)ga,
                (__attribute__((address_space(3))) void*)(As + (p * 256 + wave * 64) * 8),
                16, 0, 0);
            __builtin_amdgcn_global_load_lds(
                (const __attribute__((address_space(1))) void*)gb,
                (__attribute__((address_space(3))) void*)(Bs + (p * 256 + wave * 64) * 8),
                16, 0, 0);
        }
        __syncthreads();
        bf16x8 a[4], b[4];
        #pragma unroll
        for (int t = 0; t < 4; ++t) {
            a[t] = *(const bf16x8*)(As + (wr + t * 16 + l16) * 32 + quad * 8);
            b[t] = *(const bf16x8*)(Bs + (wc + t * 16 + l16) * 32 + quad * 8);
        }
        #pragma unroll
        for (int mt = 0; mt < 4; ++mt)
            #pragma unroll
            for (int nt = 0; nt < 4; ++nt)
                acc[mt][nt] = __builtin_amdgcn_mfma_f32_16x16x32_bf16(
                    a[mt], b[nt], acc[mt][nt], 0, 0, 0);
    }
    __syncthreads();   // all fragment reads done before smem reuse as Cs
    #pragma unroll
    for (int mt = 0; mt < 4; ++mt)
        #pragma unroll
        for (int nt = 0; nt < 4; ++nt)
            #pragma unroll
            for (int e = 0; e < 4; ++e)
                Cs[(wr + mt * 16 + quad * 4 + e) * 132 + wc + nt * 16 + l16] =
                    f2bf(acc[mt][nt][e]);
    __syncthreads();
    #pragma unroll
    for (int r8 = 0; r8 < 8; ++r8) {
        int row = r8 * 16 + (tid >> 4);
        int cc  = (tid & 15) * 8;
        const u16* p = Cs + row * 132 + cc;
        uint2 v0 = *(const uint2*)(p);
        uint2 v1 = *(const uint2*)(p + 4);
        uint4 w; w.x = v0.x; w.y = v0.y; w.z = v1.x; w.w = v1.y;
        *(uint4*)(S + (size_t)(brow + row) * BSZ + bcol + cc) = w;
    }
}

// ---------------- Kernel 2: wave-per-row stats + exact top-k + loss ----------------
// Row held in registers (16 ushort4), labels in registers (16 packed-u8 words).
// Linear 1024-bin histogram over s in (-1,1] (bin width ~0.002 => ~3 candidates
// in the threshold bin). Wave-private hist, shfl reductions, 3 barriers total.
__global__ __launch_bounds__(256) void row_stats3(const u16* __restrict__ S,
                                                  const unsigned char* __restrict__ lab8,
                                                  float* __restrict__ accum) {
    __shared__ int   hist[4][NBINS];
    __shared__ float cand[4][CAND_CAP];
    __shared__ int   ncand[4];

    const int tid = threadIdx.x, wave = tid >> 6, lane = tid & 63;
    const int i = blockIdx.x * 4 + wave;

    int* h = hist[wave];
    for (int q = lane; q < NBINS; q += 64) h[q] = 0;
    if (lane == 0) ncand[wave] = 0;

    const u32 labi = lab8[i];

    const ushort4* row4 = (const ushort4*)(S + (size_t)i * BSZ);
    const u32* lab4 = (const u32*)lab8;

    ushort4 sv[16];
    u32 lv[16];
    #pragma unroll
    for (int c = 0; c < 16; ++c) {
        sv[c] = row4[c * 64 + lane];
        lv[c] = lab4[c * 64 + lane];
    }

    float psum = 0.f, pexp = 0.f, pcntf = 0.f;
    #pragma unroll
    for (int c = 0; c < 16; ++c) {
        const int j0 = (c * 64 + lane) * 4;
        const u32 lw = lv[c];
        const u16* se = (const u16*)&sv[c];
        #pragma unroll
        for (int e = 0; e < 4; ++e) {
            const int j = j0 + e;
            if (j == i) continue;
            const float s = bf2f(se[e]);
            if (((lw >> (8 * e)) & 0xFFu) == labi) {
                pcntf += 1.f; psum += s; pexp += __expf((s - 1.f) * 10.f);
            } else {
                int bin = (int)((s + 1.0f) * (float)(NBINS / 2));
                bin = bin < 0 ? 0 : (bin > NBINS - 1 ? NBINS - 1 : bin);
                atomicAdd(&h[bin], 1);
            }
        }
    }
    __syncthreads();

    // wave suffix-scan over 1024 bins: lane owns bins [lane*16, lane*16+16)
    int local[16];
    int csum = 0;
    #pragma unroll
    for (int t = 0; t < 16; ++t) { local[t] = h[lane * 16 + t]; csum += local[t]; }
    int suf = csum;
    #pragma unroll
    for (int off = 1; off < 64; off <<= 1) {
        int t = __shfl_down(suf, off);
        if (lane + off < 64) suf += t;
    }
    const int above = suf - csum;                      // negatives in lanes above
    const bool owner = (above < K_TOP) && (suf >= K_TOP);
    int b1o = 0, c1o = 0;
    if (owner) {
        int acc2 = above;
        #pragma unroll
        for (int t = 15; t >= 0; --t) {
            if (acc2 + local[t] >= K_TOP) { b1o = lane * 16 + t; c1o = acc2; break; }
            acc2 += local[t];
        }
    }
    unsigned long long bm = __ballot(owner);
    const int src = __ffsll((long long)bm) - 1;
    const int b1 = __shfl(b1o, src);
    const int c1 = __shfl(c1o, src);                   // count strictly above bin b1

    // pass 2 (registers): exp-sum above b1; collect bin-b1 candidates
    float te = 0.f;
    #pragma unroll
    for (int c = 0; c < 16; ++c) {
        const int j0 = (c * 64 + lane) * 4;
        const u32 lw = lv[c];
        const u16* se = (const u16*)&sv[c];
        #pragma unroll
        for (int e = 0; e < 4; ++e) {
            const int j = j0 + e;
            if (j == i) continue;
            if (((lw >> (8 * e)) & 0xFFu) == labi) continue;
            const float s = bf2f(se[e]);
            int bin = (int)((s + 1.0f) * (float)(NBINS / 2));
            bin = bin < 0 ? 0 : (bin > NBINS - 1 ? NBINS - 1 : bin);
            if (bin > b1) {
                te += __expf((s - 1.f) * 10.f);
            } else if (bin == b1) {
                int p = atomicAdd(&ncand[wave], 1);
                if (p < CAND_CAP) cand[wave][p] = s;
            }
        }
    }
    __syncthreads();

    #pragma unroll
    for (int off = 32; off; off >>= 1) {
        psum  += __shfl_down(psum, off);
        pexp  += __shfl_down(pexp, off);
        pcntf += __shfl_down(pcntf, off);
        te    += __shfl_down(te, off);
    }

    if (lane == 0) {
        int nc = ncand[wave]; if (nc > CAND_CAP) nc = CAND_CAP;
        const int K2 = K_TOP - c1;                     // 1..count(b1), typically ~3
        float tsum = 0.f;
        float* cw = cand[wave];
        for (int k = 0; k < K2; ++k) {
            float mx = -4.f; int mi = 0;
            for (int q = 0; q < nc; ++q) { float v = cw[q]; if (v > mx) { mx = v; mi = q; } }
            tsum += __expf((mx - 1.f) * 10.f);         // ties equal-valued -> exact
            cw[mi] = -4.f;
        }
        if (labi > 0 && pcntf > 0.f) {
            float denom = pexp + te + tsum;
            float slp = 10.f * (psum - pcntf) - pcntf * logf(denom);
            atomicAdd(&accum[0], -2.f * slp / pcntf);
            atomicAdd(&accum[1], 1.f);
        }
    }
}

__global__ void finalize_kernel(const float* __restrict__ accum, float* __restrict__ out) {
    out[0] = accum[0] / accum[1];
}

extern "C" void kernel_launch(void* const* d_in, const int* in_sizes, int n_in,
                              void* d_out, int out_size, void* d_ws, size_t ws_size,
                              hipStream_t stream) {
    const float* F      = (const float*)d_in[0];
    const int*   labels = (const int*)d_in[1];
    float*       out    = (float*)d_out;

    u16* S              = (u16*)d_ws;                                   // 32 MB
    u16* Fb             = (u16*)((char*)d_ws + (size_t)BSZ * BSZ * 2);  // 1 MB
    unsigned char* lab8 = (unsigned char*)((char*)Fb + (size_t)BSZ * DIM * 2);
    float* accum        = (float*)(lab8 + BSZ);

    pre_kernel<<<512, 256, 0, stream>>>(F, labels, Fb, lab8, accum);
    gemm_bf16<<<dim3(32, 32), 256, 0, stream>>>(Fb, S);
    row_stats3<<<BSZ / 4, 256, 0, stream>>>(S, lab8, accum);
    finalize_kernel<<<1, 1, 0, stream>>>(accum, out);
}